// Round 1
// 9.912 us; speedup vs baseline: 1.1129x; 1.1129x over previous
//
#include <hip/hip_runtime.h>

// Problem constants: B=256, T=256, V=1000, AD=64.
#define BB 256
#define TT 256
#define ADIM 64

// out[b,t,a] = start[b,a] + (t/255) * patterns[id[b],t,a]; everything else in
// the reference is dead code. Data may arrive as fp32 or bf16 (harness decides);
// probe at runtime (current harness: bf16, absmax == 1 bf16 ulp).

typedef unsigned int  u32x4 __attribute__((ext_vector_type(4)));
typedef float         f32x4 __attribute__((ext_vector_type(4)));

static __device__ __forceinline__ float bf_lo(unsigned int u) {
    return __uint_as_float(u << 16);
}
static __device__ __forceinline__ float bf_hi(unsigned int u) {
    return __uint_as_float(u & 0xffff0000u);
}
static __device__ __forceinline__ unsigned short f32_to_bf16_rne(float f) {
    unsigned int x = __float_as_uint(f);
    unsigned int r = x + 0x7fffu + ((x >> 16) & 1u);  // round-to-nearest-even
    return (unsigned short)(r >> 16);
}
static __device__ __forceinline__ unsigned int pack_bf16(float lo, float hi) {
    return (unsigned int)f32_to_bf16_rne(lo) |
           ((unsigned int)f32_to_bf16_rne(hi) << 16);
}

// 1024 blocks x 256 threads; each thread handles 2 chunks of 8 'a'-elements
// (same b, same a0, t and t+32) -> start chunk loaded once, 2 independent
// pattern loads + 2 independent stores per lane (MLP depth 2).
__global__ __launch_bounds__(256) void traj_kernel(
    const void* __restrict__ start,     // (B, 64)   fp32 or bf16
    const int*  __restrict__ ids,       // (B,)
    const void* __restrict__ patterns,  // (V, T, 64) fp32 or bf16
    void*       __restrict__ out)       // (B, T, 64) same dtype
{
    // ---- barrier-free dtype probe. Every wave samples the SAME first 512
    // bytes of start (256 bf16-interpreted halves). If the buffer is fp32,
    // ~128 of those are fp32 low-halves -> random exponents -> some |v|>1e4
    // with overwhelming probability. Identical data -> wave-uniform result,
    // consistent across all waves; no shared mem, no __syncthreads.
    bool isbf;
    {
        const unsigned long long* q = (const unsigned long long*)start;
        unsigned long long d = q[threadIdx.x & 63];
        bool big = false;
#pragma unroll
        for (int i = 0; i < 4; ++i) {
            float v = __uint_as_float(((unsigned int)(unsigned short)(d >> (16 * i))) << 16);
            big |= !(fabsf(v) <= 1.0e4f);   // catches big values and NaN
        }
        isbf = (__ballot(big) == 0ull);
    }

    const int tid  = threadIdx.x;
    const int beta = blockIdx.x;              // 0..1023
    const int b    = beta >> 2;               // block-uniform batch index
    const int t0   = (beta & 3) << 6;         // 0,64,128,192
    const int tl   = tid >> 3;                // 0..31
    const int a0   = (tid & 7) << 3;          // 0,8,...,56

    const int   t1 = t0 + tl;
    const int   t2 = t1 + 32;
    const float w1 = (float)t1 * (1.0f / 255.0f);   // linspace(0,1,256)[t]
    const float w2 = (float)t2 * (1.0f / 255.0f);

    const int id = ids[b];                    // uniform -> s_load

    const unsigned soff  = ((unsigned)b << 6) + (unsigned)a0;
    const unsigned loff  = ((unsigned)tl << 6) + (unsigned)a0;          // lane offset in tile
    const unsigned pbase = (unsigned)id * (TT * ADIM) + ((unsigned)t0 << 6) + loff;
    const unsigned obase = (((unsigned)b * TT + (unsigned)t0) << 6) + loff;
    const unsigned step  = 32 * ADIM;         // t -> t+32, in elements

    if (isbf) {
        const unsigned short* s16 = (const unsigned short*)start + soff;
        const unsigned short* p16 = (const unsigned short*)patterns + pbase;
        unsigned short*       o16 = (unsigned short*)out + obase;

        u32x4 sv = *reinterpret_cast<const u32x4*>(s16);
        u32x4 p1 = *reinterpret_cast<const u32x4*>(p16);
        u32x4 p2 = *reinterpret_cast<const u32x4*>(p16 + step);

        u32x4 o1, o2;
#pragma unroll
        for (int i = 0; i < 4; ++i) {
            const float slo = bf_lo(sv[i]);
            const float shi = bf_hi(sv[i]);
            o1[i] = pack_bf16(fmaf(w1, bf_lo(p1[i]), slo),
                              fmaf(w1, bf_hi(p1[i]), shi));
            o2[i] = pack_bf16(fmaf(w2, bf_lo(p2[i]), slo),
                              fmaf(w2, bf_hi(p2[i]), shi));
        }
        __builtin_nontemporal_store(o1, reinterpret_cast<u32x4*>(o16));
        __builtin_nontemporal_store(o2, reinterpret_cast<u32x4*>(o16 + step));
    } else {
        const float* sf = (const float*)start + soff;
        const float* pf = (const float*)patterns + pbase;
        float*       of = (float*)out + obase;

        f32x4 s0 = ((const f32x4*)sf)[0];
        f32x4 s1 = ((const f32x4*)sf)[1];
        f32x4 a0v = ((const f32x4*)pf)[0];
        f32x4 a1v = ((const f32x4*)pf)[1];
        f32x4 b0v = ((const f32x4*)(pf + step))[0];
        f32x4 b1v = ((const f32x4*)(pf + step))[1];

        f32x4 r10, r11, r20, r21;
#pragma unroll
        for (int i = 0; i < 4; ++i) {
            r10[i] = fmaf(w1, a0v[i], s0[i]);
            r11[i] = fmaf(w1, a1v[i], s1[i]);
            r20[i] = fmaf(w2, b0v[i], s0[i]);
            r21[i] = fmaf(w2, b1v[i], s1[i]);
        }
        __builtin_nontemporal_store(r10, (f32x4*)of);
        __builtin_nontemporal_store(r11, (f32x4*)of + 1);
        __builtin_nontemporal_store(r20, (f32x4*)(of + step));
        __builtin_nontemporal_store(r21, (f32x4*)(of + step) + 1);
    }
}

extern "C" void kernel_launch(void* const* d_in, const int* in_sizes, int n_in,
                              void* d_out, int out_size, void* d_ws, size_t ws_size,
                              hipStream_t stream) {
    // setup_inputs() dict order: 0=start_state, 1=instruction_id, ..., 27=patterns
    const void* start = d_in[0];
    const int*  ids   = (const int*)d_in[1];
    int pat_idx = n_in - 1;
    // defensive: patterns is the unique input with V*T*AD = 16,384,000 elems
    for (int i = 0; i < n_in; ++i) {
        if (in_sizes[i] == 1000 * 256 * 64) { pat_idx = i; break; }
    }
    const void* patterns = d_in[pat_idx];

    // B*T*64 elems / (2 chunks x 8 elems per thread) / 256 threads = 1024 blocks
    traj_kernel<<<1024, 256, 0, stream>>>(start, ids, patterns, d_out);
}